// Round 5
// baseline (623.142 us; speedup 1.0000x reference)
//
#include <hip/hip_runtime.h>
#include <math.h>

#define D 512
#define AS1 __attribute__((address_space(1)))
#define AS3 __attribute__((address_space(3)))

typedef _Float16 f16x8 __attribute__((ext_vector_type(8)));
typedef float f32x4 __attribute__((ext_vector_type(4)));

// ---------------- Transpose: zTb[g][d][k] = fp16(h[g*32+k][d]), key-blocked ----------------
__global__ __launch_bounds__(256) void transpose_kernel(
    const float* __restrict__ h, _Float16* __restrict__ zTb, int N)
{
    __shared__ float tile[64][65];
    const int t0 = blockIdx.x * 64;
    const int d0 = blockIdx.y * 64;
    const int tid = threadIdx.x;
    const int r0 = tid >> 4;
    const int c0 = (tid & 15) * 4;
    #pragma unroll
    for (int k = 0; k < 4; k++) {
        int r = r0 + k * 16;
        float4 v = *(const float4*)(h + (size_t)(t0 + r) * D + d0 + c0);
        tile[r][c0] = v.x; tile[r][c0+1] = v.y; tile[r][c0+2] = v.z; tile[r][c0+3] = v.w;
    }
    __syncthreads();
    const int g = (t0 >> 5) + (c0 >> 5);
    const int kk = c0 & 31;
    #pragma unroll
    for (int k = 0; k < 4; k++) {
        int dd = r0 + k * 16;
        union { _Float16 hh[4]; uint2 u2; } pk;
        #pragma unroll
        for (int i = 0; i < 4; i++) pk.hh[i] = (_Float16)tile[c0 + i][dd];
        *(uint2*)(zTb + (size_t)g * 16384 + (d0 + dd) * 32 + kk) = pk.u2;
    }
}

// ---------------- Linear via fp16 MFMA: x16 = fp16(h @ W^T + b) ----------------
__global__ __launch_bounds__(256) void linear_mfma(
    const float* __restrict__ h, const float* __restrict__ W,
    const float* __restrict__ bias, _Float16* __restrict__ x16, int N)
{
    __shared__ _Float16 sA[128 * 72];
    __shared__ _Float16 sB[128 * 72];
    const int tid  = threadIdx.x;
    const int m0 = blockIdx.x * 128;
    const int n0 = blockIdx.y * 128;
    const int wave = tid >> 6, lane = tid & 63;
    const int l15 = lane & 15, quad = lane >> 4;
    const int wm = (wave >> 1) * 64, wn = (wave & 1) * 64;

    f32x4 acc[4][4];
    #pragma unroll
    for (int mi = 0; mi < 4; mi++)
        #pragma unroll
        for (int ni = 0; ni < 4; ni++) acc[mi][ni] = (f32x4){0.f,0.f,0.f,0.f};

    for (int k0 = 0; k0 < D; k0 += 64) {
        __syncthreads();
        #pragma unroll
        for (int i = 0; i < 8; i++) {
            int idx = tid + 256 * i;
            int row = idx >> 4;
            int c4  = (idx & 15) * 4;
            float4 va = *(const float4*)(h + (size_t)(m0 + row) * D + k0 + c4);
            float4 vb = *(const float4*)(W + (size_t)(n0 + row) * D + k0 + c4);
            union { _Float16 hh[4]; uint2 u2; } pa, pb;
            pa.hh[0] = (_Float16)va.x; pa.hh[1] = (_Float16)va.y;
            pa.hh[2] = (_Float16)va.z; pa.hh[3] = (_Float16)va.w;
            pb.hh[0] = (_Float16)vb.x; pb.hh[1] = (_Float16)vb.y;
            pb.hh[2] = (_Float16)vb.z; pb.hh[3] = (_Float16)vb.w;
            *(uint2*)(sA + row * 72 + c4) = pa.u2;
            *(uint2*)(sB + row * 72 + c4) = pb.u2;
        }
        __syncthreads();
        #pragma unroll
        for (int kc = 0; kc < 2; kc++) {
            f16x8 a[4], b[4];
            #pragma unroll
            for (int mi = 0; mi < 4; mi++)
                a[mi] = *(const f16x8*)(sA + (wm + mi*16 + l15)*72 + kc*32 + quad*8);
            #pragma unroll
            for (int ni = 0; ni < 4; ni++)
                b[ni] = *(const f16x8*)(sB + (wn + ni*16 + l15)*72 + kc*32 + quad*8);
            #pragma unroll
            for (int mi = 0; mi < 4; mi++)
                #pragma unroll
                for (int ni = 0; ni < 4; ni++)
                    acc[mi][ni] = __builtin_amdgcn_mfma_f32_16x16x32_f16(a[mi], b[ni], acc[mi][ni], 0, 0, 0);
        }
    }
    float bv[4];
    #pragma unroll
    for (int ni = 0; ni < 4; ni++) bv[ni] = bias[n0 + wn + ni*16 + l15];
    #pragma unroll
    for (int mi = 0; mi < 4; mi++)
        #pragma unroll
        for (int ni = 0; ni < 4; ni++)
            #pragma unroll
            for (int r = 0; r < 4; r++) {
                int row = m0 + wm + mi*16 + quad*4 + r;
                x16[(size_t)row * D + n0 + wn + ni*16 + l15] = (_Float16)(acc[mi][ni][r] + bv[ni]);
            }
}

// ---------------- Flash attention v5: single-barrier pipelined K-loop ----------------
// 2-wave WG, 32 queries. y-tile double-buffered in LDS (DMA prefetch of kblock+1
// issued right after the barrier that frees the buffer). PV B-fragments read
// directly from blocked zTb (1 KB contiguous per wave-instruction) -> no z LDS,
// no second/third barrier. P scratch is wave-private.
__global__ __launch_bounds__(128, 1) void attn5_kernel(
    const float* __restrict__ h, const _Float16* __restrict__ x16,
    const _Float16* __restrict__ zTb, const int* __restrict__ lens,
    float* __restrict__ out, int N, int B)
{
    __shared__ __align__(16) unsigned char smem[69120];
    _Float16* ybuf = (_Float16*)smem;            // 2 x [32][520] = 66560 B
    _Float16* pbuf = (_Float16*)(smem + 66560);  // 2 waves x [16][40] = 2560 B

    const int is64 = (lens[1] == 0 && lens[3] == 0) ? 1 : 0;

    // longest-first block -> (segment, qtile)
    int blk = blockIdx.x;
    int seg = -1, tile = 0;
    {
        int acc = 0;
        for (int t = 0; t < B; t++) {
            int s = B - 1 - t;
            int Ls = is64 ? lens[2 * s] : lens[s];
            int nt = (Ls + 31) >> 5;
            if (seg < 0 && blk < acc + nt) { seg = s; tile = blk - acc; }
            acc += nt;
        }
    }
    if (seg < 0) return;
    int off = 0;
    for (int t = 0; t < seg; t++) off += is64 ? lens[2 * t] : lens[t];
    const int len = is64 ? lens[2 * seg] : lens[seg];

    const int tid  = threadIdx.x;
    const int wv   = tid >> 6;
    const int lane = tid & 63;
    const int l15  = lane & 15;
    const int quad = lane >> 4;

    // Q A-fragments: 16 queries of this wave (m = l15)
    f16x8 Qf[16];
    {
        int qr = off + tile * 32 + wv * 16 + l15;
        if (qr > N - 1) qr = N - 1;
        const float* hr = h + (size_t)qr * D;
        #pragma unroll
        for (int c = 0; c < 16; c++) {
            float4 u = *(const float4*)(hr + c * 32 + quad * 8);
            float4 v = *(const float4*)(hr + c * 32 + quad * 8 + 4);
            f16x8 q;
            q[0] = (_Float16)u.x; q[1] = (_Float16)u.y; q[2] = (_Float16)u.z; q[3] = (_Float16)u.w;
            q[4] = (_Float16)v.x; q[5] = (_Float16)v.y; q[6] = (_Float16)v.z; q[7] = (_Float16)v.w;
            Qf[c] = q;
        }
    }

    f32x4 O[32];
    #pragma unroll
    for (int f = 0; f < 32; f++) O[f] = (f32x4){0.f,0.f,0.f,0.f};
    float mR[4] = {-1e30f,-1e30f,-1e30f,-1e30f};
    float lR[4] = {0.f,0.f,0.f,0.f};

    _Float16* Pw = pbuf + wv * 640;
    const int nkb = (len + 31) >> 5;

    // ---- prologue: stage kblock 0 into buffer 0 ----
    #pragma unroll
    for (int i = 0; i < 16; i++) {
        int r = wv * 16 + i;
        int gr = off + r; if (gr > N - 1) gr = N - 1;
        const _Float16* gsrc = x16 + (size_t)gr * D + lane * 8;
        __builtin_amdgcn_global_load_lds((const AS1 unsigned int*)gsrc,
                                         (AS3 unsigned int*)(ybuf + r * 520), 16, 0, 0);
    }

    int cur = 0;
    for (int kb = 0; kb < nkb; kb++) {
        const int j0 = kb * 32;
        __syncthreads();   // drains DMA(kb) [issued ~1 kblock ago]; frees buf[cur^1]

        // ---- prefetch kblock+1 into the freed buffer ----
        if (kb + 1 < nkb) {
            const int jn = (kb + 1) * 32;
            _Float16* dst = ybuf + (cur ^ 1) * 16640;
            #pragma unroll
            for (int i = 0; i < 16; i++) {
                int r = wv * 16 + i;
                int gr = off + jn + r; if (gr > N - 1) gr = N - 1;
                const _Float16* gsrc = x16 + (size_t)gr * D + lane * 8;
                __builtin_amdgcn_global_load_lds((const AS1 unsigned int*)gsrc,
                                                 (AS3 unsigned int*)(dst + r * 520), 16, 0, 0);
            }
        }

        // ---- scores from resident buffer ----
        const _Float16* yb = ybuf + cur * 16640;
        f32x4 s0 = (f32x4){0.f,0.f,0.f,0.f}, s1 = (f32x4){0.f,0.f,0.f,0.f};
        #pragma unroll
        for (int c = 0; c < 16; c++) {
            f16x8 b0 = *(const f16x8*)(yb + l15 * 520 + c * 32 + quad * 8);
            f16x8 b1 = *(const f16x8*)(yb + (16 + l15) * 520 + c * 32 + quad * 8);
            s0 = __builtin_amdgcn_mfma_f32_16x16x32_f16(Qf[c], b0, s0, 0, 0, 0);
            s1 = __builtin_amdgcn_mfma_f32_16x16x32_f16(Qf[c], b1, s1, 0, 0, 0);
        }
        const int kk0 = j0 + l15, kk1 = j0 + 16 + l15;
        #pragma unroll
        for (int r = 0; r < 4; r++) {
            if (kk0 >= len) s0[r] = -1e30f;
            if (kk1 >= len) s1[r] = -1e30f;
        }

        // ---- online softmax (wave-private) ----
        float al[4];
        bool need = false;
        #pragma unroll
        for (int r = 0; r < 4; r++) {
            float t = fmaxf(s0[r], s1[r]);
            t = fmaxf(t, __shfl_xor(t, 1, 16));
            t = fmaxf(t, __shfl_xor(t, 2, 16));
            t = fmaxf(t, __shfl_xor(t, 4, 16));
            t = fmaxf(t, __shfl_xor(t, 8, 16));
            float mn = fmaxf(mR[r], t);
            al[r] = __expf(mR[r] - mn);
            mR[r] = mn;
            float e0 = __expf(s0[r] - mn);
            float e1 = __expf(s1[r] - mn);
            float ps = e0 + e1;
            ps += __shfl_xor(ps, 1, 16);
            ps += __shfl_xor(ps, 2, 16);
            ps += __shfl_xor(ps, 4, 16);
            ps += __shfl_xor(ps, 8, 16);
            lR[r] = lR[r] * al[r] + ps;
            Pw[(quad * 4 + r) * 40 + l15]      = (_Float16)e0;
            Pw[(quad * 4 + r) * 40 + 16 + l15] = (_Float16)e1;
            need |= (al[r] != 1.0f);
        }
        if (__ballot(need)) {
            f32x4 av; av[0] = al[0]; av[1] = al[1]; av[2] = al[2]; av[3] = al[3];
            #pragma unroll
            for (int f = 0; f < 32; f++) O[f] *= av;
        }
        f16x8 pf = *(const f16x8*)(Pw + l15 * 40 + quad * 8);

        // ---- PV: B-fragments straight from blocked zTb (coalesced 1KB/instr) ----
        const _Float16* zsrc = zTb + (size_t)((off + j0) >> 5) * 16384 + l15 * 32 + quad * 8;
        #pragma unroll
        for (int f = 0; f < 32; f++) {
            f16x8 zf = *(const f16x8*)(zsrc + f * 512);
            O[f] = __builtin_amdgcn_mfma_f32_16x16x32_f16(pf, zf, O[f], 0, 0, 0);
        }
        cur ^= 1;
    }

    // ---- epilogue ----
    float inv[4];
    #pragma unroll
    for (int r = 0; r < 4; r++) inv[r] = 1.0f / lR[r];
    #pragma unroll
    for (int r = 0; r < 4; r++) {
        int qloc = tile * 32 + wv * 16 + quad * 4 + r;
        if (qloc < len) {
            float* orow = out + (size_t)(off + qloc) * D + l15;
            #pragma unroll
            for (int f = 0; f < 32; f++) orow[f * 16] = O[f][r] * inv[r];
        }
    }
}

extern "C" void kernel_launch(void* const* d_in, const int* in_sizes, int n_in,
                              void* d_out, int out_size, void* d_ws, size_t ws_size,
                              hipStream_t stream) {
    const float* h    = (const float*)d_in[0];
    const float* W    = (const float*)d_in[1];
    const float* bias = (const float*)d_in[2];
    const int*   lens = (const int*)d_in[3];
    float* outp = (float*)d_out;

    const int N = in_sizes[0] / D;                 // 24064
    int B = in_sizes[3]; if (B > 16) B = 16;

    _Float16* x16 = (_Float16*)d_ws;                                  // N*D fp16
    _Float16* zTb = (_Float16*)((char*)d_ws + (size_t)N * D * 2);     // blocked z^T fp16

    dim3 g2(N / 64, D / 64);
    transpose_kernel<<<g2, 256, 0, stream>>>(h, zTb, N);

    dim3 g1(N / 128, D / 128);
    linear_mfma<<<g1, 256, 0, stream>>>(h, W, bias, x16, N);

    const int nblk = N / 32 + B;
    attn5_kernel<<<nblk, 128, 0, stream>>>(h, x16, zTb, lens, outp, N, B);
}

// Round 6
// 437.504 us; speedup vs baseline: 1.4243x; 1.4243x over previous
//
#include <hip/hip_runtime.h>
#include <math.h>

#define D 512
#define AS1 __attribute__((address_space(1)))
#define AS3 __attribute__((address_space(3)))

typedef _Float16 f16x8 __attribute__((ext_vector_type(8)));
typedef float f32x4 __attribute__((ext_vector_type(4)));

// ---------------- Transpose: zTb[g][d][kk_swz] = fp16(h[g*32+k][d]) ----------------
// Key-blocked (g = row/32) AND granule-swizzled so the attn kernel can DMA the
// 16KB block contiguously into LDS and read PV B-frags conflict-free:
//   granule (16B = 8 keys) for (d, kg) stored at position ((kg + (d>>1)) & 3).
__global__ __launch_bounds__(256) void transpose_kernel(
    const float* __restrict__ h, _Float16* __restrict__ zTb, int N)
{
    __shared__ float tile[64][65];
    const int t0 = blockIdx.x * 64;
    const int d0 = blockIdx.y * 64;
    const int tid = threadIdx.x;
    const int r0 = tid >> 4;
    const int c0 = (tid & 15) * 4;
    #pragma unroll
    for (int k = 0; k < 4; k++) {
        int r = r0 + k * 16;
        float4 v = *(const float4*)(h + (size_t)(t0 + r) * D + d0 + c0);
        tile[r][c0] = v.x; tile[r][c0+1] = v.y; tile[r][c0+2] = v.z; tile[r][c0+3] = v.w;
    }
    __syncthreads();
    const int g = (t0 >> 5) + (c0 >> 5);
    const int kk = c0 & 31;                 // key-in-block, {0,4,8,...,28}
    const int kg = kk >> 3;                 // granule 0..3
    const int sub = kk & 7;                 // 8B sub-offset within granule
    #pragma unroll
    for (int k = 0; k < 4; k++) {
        int dd = d0 + r0 + k * 16;          // global dim
        int kks = ((kg + (dd >> 1)) & 3) * 8 + sub;
        union { _Float16 hh[4]; uint2 u2; } pk;
        #pragma unroll
        for (int i = 0; i < 4; i++) pk.hh[i] = (_Float16)tile[c0 + i][r0 + k * 16];
        *(uint2*)(zTb + (size_t)g * 16384 + dd * 32 + kks) = pk.u2;
    }
}

// ---------------- Linear via fp16 MFMA: x16 = fp16(h @ W^T + b) ----------------
__global__ __launch_bounds__(256) void linear_mfma(
    const float* __restrict__ h, const float* __restrict__ W,
    const float* __restrict__ bias, _Float16* __restrict__ x16, int N)
{
    __shared__ _Float16 sA[128 * 72];
    __shared__ _Float16 sB[128 * 72];
    const int tid  = threadIdx.x;
    const int m0 = blockIdx.x * 128;
    const int n0 = blockIdx.y * 128;
    const int wave = tid >> 6, lane = tid & 63;
    const int l15 = lane & 15, quad = lane >> 4;
    const int wm = (wave >> 1) * 64, wn = (wave & 1) * 64;

    f32x4 acc[4][4];
    #pragma unroll
    for (int mi = 0; mi < 4; mi++)
        #pragma unroll
        for (int ni = 0; ni < 4; ni++) acc[mi][ni] = (f32x4){0.f,0.f,0.f,0.f};

    for (int k0 = 0; k0 < D; k0 += 64) {
        __syncthreads();
        #pragma unroll
        for (int i = 0; i < 8; i++) {
            int idx = tid + 256 * i;
            int row = idx >> 4;
            int c4  = (idx & 15) * 4;
            float4 va = *(const float4*)(h + (size_t)(m0 + row) * D + k0 + c4);
            float4 vb = *(const float4*)(W + (size_t)(n0 + row) * D + k0 + c4);
            union { _Float16 hh[4]; uint2 u2; } pa, pb;
            pa.hh[0] = (_Float16)va.x; pa.hh[1] = (_Float16)va.y;
            pa.hh[2] = (_Float16)va.z; pa.hh[3] = (_Float16)va.w;
            pb.hh[0] = (_Float16)vb.x; pb.hh[1] = (_Float16)vb.y;
            pb.hh[2] = (_Float16)vb.z; pb.hh[3] = (_Float16)vb.w;
            *(uint2*)(sA + row * 72 + c4) = pa.u2;
            *(uint2*)(sB + row * 72 + c4) = pb.u2;
        }
        __syncthreads();
        #pragma unroll
        for (int kc = 0; kc < 2; kc++) {
            f16x8 a[4], b[4];
            #pragma unroll
            for (int mi = 0; mi < 4; mi++)
                a[mi] = *(const f16x8*)(sA + (wm + mi*16 + l15)*72 + kc*32 + quad*8);
            #pragma unroll
            for (int ni = 0; ni < 4; ni++)
                b[ni] = *(const f16x8*)(sB + (wn + ni*16 + l15)*72 + kc*32 + quad*8);
            #pragma unroll
            for (int mi = 0; mi < 4; mi++)
                #pragma unroll
                for (int ni = 0; ni < 4; ni++)
                    acc[mi][ni] = __builtin_amdgcn_mfma_f32_16x16x32_f16(a[mi], b[ni], acc[mi][ni], 0, 0, 0);
        }
    }
    float bv[4];
    #pragma unroll
    for (int ni = 0; ni < 4; ni++) bv[ni] = bias[n0 + wn + ni*16 + l15];
    #pragma unroll
    for (int mi = 0; mi < 4; mi++)
        #pragma unroll
        for (int ni = 0; ni < 4; ni++)
            #pragma unroll
            for (int r = 0; r < 4; r++) {
                int row = m0 + wm + mi*16 + quad*4 + r;
                x16[(size_t)row * D + n0 + wn + ni*16 + l15] = (_Float16)(acc[mi][ni][r] + bv[ni]);
            }
}

// ---------------- Flash attention v6: 2-barrier pipelined K-loop ----------------
// Fixed-role buffers: ybuf (scores operand), zbuf (PV operand, swizzled).
// stage z(kb) -> scores(kb) -> BAR1 (z landed) -> stage y(kb+1) -> PV(kb) -> BAR2.
// Every DMA has a full compute phase to land before its consuming barrier.
__global__ __launch_bounds__(128, 1) void attn6_kernel(
    const float* __restrict__ h, const _Float16* __restrict__ x16,
    const _Float16* __restrict__ zTb, const int* __restrict__ lens,
    float* __restrict__ out, int N, int B)
{
    __shared__ __align__(16) unsigned char smem[68608];
    _Float16* ybuf = (_Float16*)smem;            // [32][520] = 33280 B
    _Float16* zbuf = (_Float16*)(smem + 33280);  // [512][32] swizzled = 32768 B
    _Float16* pbuf = (_Float16*)(smem + 66048);  // 2 x [16][40] = 2560 B

    const int is64 = (lens[1] == 0 && lens[3] == 0) ? 1 : 0;

    // longest-first block -> (segment, qtile)
    int blk = blockIdx.x;
    int seg = -1, tile = 0;
    {
        int acc = 0;
        for (int t = 0; t < B; t++) {
            int s = B - 1 - t;
            int Ls = is64 ? lens[2 * s] : lens[s];
            int nt = (Ls + 31) >> 5;
            if (seg < 0 && blk < acc + nt) { seg = s; tile = blk - acc; }
            acc += nt;
        }
    }
    if (seg < 0) return;
    int off = 0;
    for (int t = 0; t < seg; t++) off += is64 ? lens[2 * t] : lens[t];
    const int len = is64 ? lens[2 * seg] : lens[seg];

    const int tid  = threadIdx.x;
    const int wv   = tid >> 6;
    const int lane = tid & 63;
    const int l15  = lane & 15;
    const int quad = lane >> 4;
    // lane-constant swizzled key-group column for PV reads (halves)
    const int zcol = ((quad + (l15 >> 1)) & 3) * 8;

    // Q A-fragments: 16 queries of this wave (m = l15)
    f16x8 Qf[16];
    {
        int qr = off + tile * 32 + wv * 16 + l15;
        if (qr > N - 1) qr = N - 1;
        const float* hr = h + (size_t)qr * D;
        #pragma unroll
        for (int c = 0; c < 16; c++) {
            float4 u = *(const float4*)(hr + c * 32 + quad * 8);
            float4 v = *(const float4*)(hr + c * 32 + quad * 8 + 4);
            f16x8 q;
            q[0] = (_Float16)u.x; q[1] = (_Float16)u.y; q[2] = (_Float16)u.z; q[3] = (_Float16)u.w;
            q[4] = (_Float16)v.x; q[5] = (_Float16)v.y; q[6] = (_Float16)v.z; q[7] = (_Float16)v.w;
            Qf[c] = q;
        }
    }

    f32x4 O[32];
    #pragma unroll
    for (int f = 0; f < 32; f++) O[f] = (f32x4){0.f,0.f,0.f,0.f};
    float mR[4] = {-1e30f,-1e30f,-1e30f,-1e30f};
    float lR[4] = {0.f,0.f,0.f,0.f};

    _Float16* Pw = pbuf + wv * 640;
    const int nkb = (len + 31) >> 5;

    // ---- prologue: stage y(0) ----
    #pragma unroll
    for (int i = 0; i < 16; i++) {
        int r = wv * 16 + i;
        int gr = off + r; if (gr > N - 1) gr = N - 1;
        const _Float16* gsrc = x16 + (size_t)gr * D + lane * 8;
        __builtin_amdgcn_global_load_lds((const AS1 unsigned int*)gsrc,
                                         (AS3 unsigned int*)(ybuf + r * 520), 16, 0, 0);
    }
    __syncthreads();   // y(0) resident

    for (int kb = 0; kb < nkb; kb++) {
        const int j0 = kb * 32;

        // ---- stage z(kb): identity copy of swizzled 16KB block ----
        {
            const _Float16* zsrc = zTb + (size_t)((off + j0) >> 5) * 16384;
            #pragma unroll
            for (int i = 0; i < 16; i++) {
                int half_off = (wv * 16 + i) * 512 + lane * 8;
                __builtin_amdgcn_global_load_lds((const AS1 unsigned int*)(zsrc + half_off),
                                                 (AS3 unsigned int*)(zbuf + half_off), 16, 0, 0);
            }
        }

        // ---- scores from ybuf ----
        f32x4 s0 = (f32x4){0.f,0.f,0.f,0.f}, s1 = (f32x4){0.f,0.f,0.f,0.f};
        #pragma unroll
        for (int c = 0; c < 16; c++) {
            f16x8 b0 = *(const f16x8*)(ybuf + l15 * 520 + c * 32 + quad * 8);
            f16x8 b1 = *(const f16x8*)(ybuf + (16 + l15) * 520 + c * 32 + quad * 8);
            s0 = __builtin_amdgcn_mfma_f32_16x16x32_f16(Qf[c], b0, s0, 0, 0, 0);
            s1 = __builtin_amdgcn_mfma_f32_16x16x32_f16(Qf[c], b1, s1, 0, 0, 0);
        }
        const int kk0 = j0 + l15, kk1 = j0 + 16 + l15;
        #pragma unroll
        for (int r = 0; r < 4; r++) {
            if (kk0 >= len) s0[r] = -1e30f;
            if (kk1 >= len) s1[r] = -1e30f;
        }

        // ---- online softmax (wave-private) ----
        float al[4];
        bool need = false;
        #pragma unroll
        for (int r = 0; r < 4; r++) {
            float t = fmaxf(s0[r], s1[r]);
            t = fmaxf(t, __shfl_xor(t, 1, 16));
            t = fmaxf(t, __shfl_xor(t, 2, 16));
            t = fmaxf(t, __shfl_xor(t, 4, 16));
            t = fmaxf(t, __shfl_xor(t, 8, 16));
            float mn = fmaxf(mR[r], t);
            al[r] = __expf(mR[r] - mn);
            mR[r] = mn;
            float e0 = __expf(s0[r] - mn);
            float e1 = __expf(s1[r] - mn);
            float ps = e0 + e1;
            ps += __shfl_xor(ps, 1, 16);
            ps += __shfl_xor(ps, 2, 16);
            ps += __shfl_xor(ps, 4, 16);
            ps += __shfl_xor(ps, 8, 16);
            lR[r] = lR[r] * al[r] + ps;
            Pw[(quad * 4 + r) * 40 + l15]      = (_Float16)e0;
            Pw[(quad * 4 + r) * 40 + 16 + l15] = (_Float16)e1;
            need |= (al[r] != 1.0f);
        }

        __syncthreads();   // BAR1: z(kb) landed (covered by scores); ybuf free

        // ---- stage y(kb+1) into ybuf ----
        if (kb + 1 < nkb) {
            const int jn = (kb + 1) * 32;
            #pragma unroll
            for (int i = 0; i < 16; i++) {
                int r = wv * 16 + i;
                int gr = off + jn + r; if (gr > N - 1) gr = N - 1;
                const _Float16* gsrc = x16 + (size_t)gr * D + lane * 8;
                __builtin_amdgcn_global_load_lds((const AS1 unsigned int*)gsrc,
                                                 (AS3 unsigned int*)(ybuf + r * 520), 16, 0, 0);
            }
        }

        // ---- rescale O, read P ----
        if (__ballot(need)) {
            f32x4 av; av[0] = al[0]; av[1] = al[1]; av[2] = al[2]; av[3] = al[3];
            #pragma unroll
            for (int f = 0; f < 32; f++) O[f] *= av;
        }
        f16x8 pf = *(const f16x8*)(Pw + l15 * 40 + quad * 8);

        // ---- PV from zbuf (swizzled, conflict-free) ----
        #pragma unroll
        for (int f = 0; f < 32; f++) {
            f16x8 zf = *(const f16x8*)(zbuf + (f * 16 + l15) * 32 + zcol);
            O[f] = __builtin_amdgcn_mfma_f32_16x16x32_f16(pf, zf, O[f], 0, 0, 0);
        }

        __syncthreads();   // BAR2: y(kb+1) landed (covered by PV); zbuf free
    }

    // ---- epilogue ----
    float inv[4];
    #pragma unroll
    for (int r = 0; r < 4; r++) inv[r] = 1.0f / lR[r];
    #pragma unroll
    for (int r = 0; r < 4; r++) {
        int qloc = tile * 32 + wv * 16 + quad * 4 + r;
        if (qloc < len) {
            float* orow = out + (size_t)(off + qloc) * D + l15;
            #pragma unroll
            for (int f = 0; f < 32; f++) orow[f * 16] = O[f][r] * inv[r];
        }
    }
}

extern "C" void kernel_launch(void* const* d_in, const int* in_sizes, int n_in,
                              void* d_out, int out_size, void* d_ws, size_t ws_size,
                              hipStream_t stream) {
    const float* h    = (const float*)d_in[0];
    const float* W    = (const float*)d_in[1];
    const float* bias = (const float*)d_in[2];
    const int*   lens = (const int*)d_in[3];
    float* outp = (float*)d_out;

    const int N = in_sizes[0] / D;                 // 24064
    int B = in_sizes[3]; if (B > 16) B = 16;

    _Float16* x16 = (_Float16*)d_ws;                                  // N*D fp16
    _Float16* zTb = (_Float16*)((char*)d_ws + (size_t)N * D * 2);     // blocked+swizzled z^T

    dim3 g2(N / 64, D / 64);
    transpose_kernel<<<g2, 256, 0, stream>>>(h, zTb, N);

    dim3 g1(N / 128, D / 128);
    linear_mfma<<<g1, 256, 0, stream>>>(h, W, bias, x16, N);

    const int nblk = N / 32 + B;
    attn6_kernel<<<nblk, 128, 0, stream>>>(h, x16, zTb, lens, outp, N, B);
}